// Round 6
// baseline (1085.554 us; speedup 1.0000x reference)
//
#include <hip/hip_runtime.h>

#define DIM 128
#define LSZ 100000
#define CSZ 210000
#define ESZ 630000
#define CH  16384   // ushorts per 128x128 weight chunk

typedef __attribute__((ext_vector_type(8))) short short8;
typedef __attribute__((ext_vector_type(4))) float f32x4;

__device__ __forceinline__ ushort f2b(float x) {          // fp32 -> bf16 RNE
    unsigned u = __float_as_uint(x);
    return (ushort)((u + 0x7FFFu + ((u >> 16) & 1)) >> 16);
}
__device__ __forceinline__ float b2f(unsigned lo16) {     // bf16 (low bits) -> fp32
    return __uint_as_float(lo16 << 16);
}
// swizzled byte offset of 16B chunk `c` (0..15) in row `row` of a [128][128]bf16 LDS tile
__device__ __forceinline__ int lds_off(int row, int c) {
    return row * 256 + ((c ^ (row & 7)) << 4);
}
// async global->LDS 16B: per-lane global src, wave-uniform LDS base (+lane*16 implicit)
__device__ __forceinline__ void gload_lds16(const void* g, void* l) {
    __builtin_amdgcn_global_load_lds(
        (const __attribute__((address_space(1))) unsigned*)g,
        (__attribute__((address_space(3))) unsigned*)l, 16, 0, 0);
}
// REQUIRED before any __syncthreads() that publishes LDS-DMA results.
__device__ __forceinline__ void vm_drain() {
    asm volatile("s_waitcnt vmcnt(0)" ::: "memory");
}

// shared K=128 inner loop: 4 k-steps x 16 MFMA
__device__ __forceinline__ void kloop128(const char* Xs, const char* Ws,
                                         int wr, int wc, int lane, f32x4 (&acc)[4][4])
{
    #pragma unroll
    for (int ks = 0; ks < 4; ++ks) {
        int kc = ks * 4 + (lane >> 4);
        short8 af[4], bfr[4];
        #pragma unroll
        for (int m = 0; m < 4; ++m) {
            int row = wr * 64 + m * 16 + (lane & 15);
            af[m] = *(const short8*)(Xs + lds_off(row, kc));
        }
        #pragma unroll
        for (int n = 0; n < 4; ++n) {
            int col = wc * 64 + n * 16 + (lane & 15);
            bfr[n] = *(const short8*)(Ws + lds_off(col, kc));
        }
        #pragma unroll
        for (int m = 0; m < 4; ++m)
            #pragma unroll
            for (int n = 0; n < 4; ++n)
                acc[m][n] = __builtin_amdgcn_mfma_f32_16x16x32_bf16(af[m], bfr[n], acc[m][n], 0, 0, 0);
    }
}

// stage a full 128x128 bf16 tile via global_load_lds, source pre-swizzled.
template<bool SWAPROW>
__device__ __forceinline__ void stage_tile_fast(const ushort* __restrict__ G, size_t grow0,
                                                char* L, int wid, int lane)
{
    #pragma unroll
    for (int g = 0; g < 8; ++g) {
        int row0 = wid * 32 + g * 4;
        int row  = row0 + (lane >> 4);
        size_t grow = grow0 + (size_t)(SWAPROW ? (row ^ 1) : row);
        const ushort* src = G + grow * DIM + (((lane & 15) ^ (row & 7)) << 3);
        gload_lds16(src, L + row0 * 256);
    }
}

// ---------------------------------------------------------------------------
// Fused 2-layer MLP + optional per-row attention dot of the fp32 output.
// ---------------------------------------------------------------------------
template<bool SWAP, bool DOT>
__launch_bounds__(256)
__global__ void mlp2_fused(const ushort* __restrict__ X,
                           const ushort* __restrict__ Wt1, const ushort* __restrict__ Wt2,
                           const float* __restrict__ b1, const float* __restrict__ b2,
                           ushort* __restrict__ Yb,
                           const float* __restrict__ attp, float* __restrict__ dotout,
                           int M)
{
    __shared__ char smem[65536];
    char* Xs = smem;
    char* Ws = smem + 32768;
    const int tid  = threadIdx.x;
    const int lane = tid & 63;
    const int wid  = tid >> 6;
    const int wr = wid >> 1, wc = wid & 1;
    const int r0t = blockIdx.x * 128;
    const bool full = (r0t + 128 <= M);

    if (full) {
        stage_tile_fast<SWAP>(X, (size_t)r0t, Xs, wid, lane);
        stage_tile_fast<false>(Wt1, 0, Ws, wid, lane);
        vm_drain();
    } else {
        #pragma unroll
        for (int i = 0; i < 8; ++i) {
            int id = i * 256 + tid;
            int row = id >> 4, c = id & 15;
            int gr = r0t + row;
            short8 v = {0,0,0,0,0,0,0,0};
            if (gr < M) {
                int sr = SWAP ? (gr ^ 1) : gr;
                v = *(const short8*)(X + (size_t)sr * DIM + c * 8);
            }
            *(short8*)(Xs + lds_off(row, c)) = v;
            *(short8*)(Ws + lds_off(row, c)) = *(const short8*)(Wt1 + row * DIM + c * 8);
        }
    }
    __syncthreads();

    f32x4 acc[4][4];
    #pragma unroll
    for (int m = 0; m < 4; ++m)
        #pragma unroll
        for (int n = 0; n < 4; ++n) acc[m][n] = (f32x4){0.f, 0.f, 0.f, 0.f};

    kloop128(Xs, Ws, wr, wc, lane, acc);
    __syncthreads();                       // all LDS reads of X/W1 done

    stage_tile_fast<false>(Wt2, 0, Ws, wid, lane);
    {
        const int col0 = wc * 64 + (lane & 15);
        float b1v[4];
        #pragma unroll
        for (int n = 0; n < 4; ++n) b1v[n] = b1[col0 + n * 16];
        #pragma unroll
        for (int m = 0; m < 4; ++m)
            #pragma unroll
            for (int i = 0; i < 4; ++i) {
                int row = wr * 64 + m * 16 + (lane >> 4) * 4 + i;
                #pragma unroll
                for (int n = 0; n < 4; ++n) {
                    float v = fmaxf(acc[m][n][i] + b1v[n], 0.f);
                    int cb = (col0 + n * 16) * 2;
                    *(ushort*)(Xs + row * 256 + (((cb >> 4) ^ (row & 7)) << 4) + (cb & 15)) = f2b(v);
                }
            }
    }
    vm_drain();
    __syncthreads();

    #pragma unroll
    for (int m = 0; m < 4; ++m)
        #pragma unroll
        for (int n = 0; n < 4; ++n) acc[m][n] = (f32x4){0.f, 0.f, 0.f, 0.f};

    kloop128(Xs, Ws, wr, wc, lane, acc);

    const int col0 = wc * 64 + (lane & 15);
    float b2v[4], attv[4];
    #pragma unroll
    for (int n = 0; n < 4; ++n) b2v[n] = b2[col0 + n * 16];
    if (DOT)
        #pragma unroll
        for (int n = 0; n < 4; ++n) attv[n] = attp[col0 + n * 16];

    float ps[4][4];
    #pragma unroll
    for (int m = 0; m < 4; ++m)
        #pragma unroll
        for (int i = 0; i < 4; ++i) {
            int gr = r0t + wr * 64 + m * 16 + (lane >> 4) * 4 + i;
            float p = 0.f;
            #pragma unroll
            for (int n = 0; n < 4; ++n) {
                float y = acc[m][n][i] + b2v[n];
                if (gr < M) Yb[(size_t)gr * DIM + col0 + n * 16] = f2b(y);
                if (DOT) p = fmaf(y, attv[n], p);
            }
            ps[m][i] = p;
        }

    if (DOT) {
        #pragma unroll
        for (int mask = 1; mask <= 8; mask <<= 1)
            #pragma unroll
            for (int m = 0; m < 4; ++m)
                #pragma unroll
                for (int i = 0; i < 4; ++i)
                    ps[m][i] += __shfl_xor(ps[m][i], mask);
        __syncthreads();
        float* part = (float*)smem;        // [2][128]
        if ((lane & 15) == 0)
            #pragma unroll
            for (int m = 0; m < 4; ++m)
                #pragma unroll
                for (int i = 0; i < 4; ++i)
                    part[wc * 128 + wr * 64 + m * 16 + (lane >> 4) * 4 + i] = ps[m][i];
        __syncthreads();
        if (tid < 128) {
            int gr = r0t + tid;
            if (gr < M) dotout[gr] = part[tid] + part[128 + tid];
        }
    }
}

// ---------------------------------------------------------------------------
// Update GEMM: Y = concat_K(X1..XNIN) @ W + bias.
// WRITEBF: also write bf16 mirror (next iter).  DOT: per-row attention dot.
// ---------------------------------------------------------------------------
template<int NIN, bool WRITEBF, bool DOT>
__launch_bounds__(256)
__global__ void upd_gemm(const ushort* __restrict__ X1, const ushort* __restrict__ X2,
                         const ushort* __restrict__ X3,
                         const ushort* __restrict__ Wt, const float* __restrict__ bias,
                         float* __restrict__ Yf, ushort* __restrict__ Yb,
                         const float* __restrict__ attp, float* __restrict__ dotout,
                         int M)
{
    __shared__ char smem[65536];
    char* Xs = smem;
    char* Ws = smem + 32768;
    const int tid  = threadIdx.x;
    const int lane = tid & 63;
    const int wid  = tid >> 6;
    const int wr = wid >> 1, wc = wid & 1;
    const int r0t = blockIdx.x * 128;
    const bool full = (r0t + 128 <= M);

    f32x4 acc[4][4];
    #pragma unroll
    for (int m = 0; m < 4; ++m)
        #pragma unroll
        for (int n = 0; n < 4; ++n) acc[m][n] = (f32x4){0.f, 0.f, 0.f, 0.f};

    #pragma unroll
    for (int in = 0; in < NIN; ++in) {
        const ushort* X = (in == 0) ? X1 : ((in == 1) ? X2 : X3);
        __syncthreads();
        if (full) {
            stage_tile_fast<false>(X, (size_t)r0t, Xs, wid, lane);
            stage_tile_fast<false>(Wt + (size_t)in * CH, 0, Ws, wid, lane);
            vm_drain();
        } else {
            #pragma unroll
            for (int i = 0; i < 8; ++i) {
                int id = i * 256 + tid;
                int row = id >> 4, c = id & 15;
                int gr = r0t + row;
                short8 v = {0,0,0,0,0,0,0,0};
                if (gr < M) v = *(const short8*)(X + (size_t)gr * DIM + c * 8);
                *(short8*)(Xs + lds_off(row, c)) = v;
                *(short8*)(Ws + lds_off(row, c)) =
                    *(const short8*)(Wt + (size_t)in * CH + row * DIM + c * 8);
            }
        }
        __syncthreads();
        kloop128(Xs, Ws, wr, wc, lane, acc);
    }

    const int col0 = wc * 64 + (lane & 15);
    float bv[4], attv[4];
    #pragma unroll
    for (int n = 0; n < 4; ++n) bv[n] = bias[col0 + n * 16];
    if (DOT)
        #pragma unroll
        for (int n = 0; n < 4; ++n) attv[n] = attp[col0 + n * 16];

    float ps[4][4];
    #pragma unroll
    for (int m = 0; m < 4; ++m)
        #pragma unroll
        for (int i = 0; i < 4; ++i) {
            int gr = r0t + wr * 64 + m * 16 + (lane >> 4) * 4 + i;
            float p = 0.f;
            #pragma unroll
            for (int n = 0; n < 4; ++n) {
                float v = acc[m][n][i] + bv[n];
                if (gr < M) {
                    Yf[(size_t)gr * DIM + col0 + n * 16] = v;
                    if (WRITEBF) Yb[(size_t)gr * DIM + col0 + n * 16] = f2b(v);
                }
                if (DOT) p = fmaf(v, attv[n], p);
            }
            ps[m][i] = p;
        }

    if (DOT) {
        #pragma unroll
        for (int mask = 1; mask <= 8; mask <<= 1)
            #pragma unroll
            for (int m = 0; m < 4; ++m)
                #pragma unroll
                for (int i = 0; i < 4; ++i)
                    ps[m][i] += __shfl_xor(ps[m][i], mask);
        __syncthreads();
        float* part = (float*)smem;
        if ((lane & 15) == 0)
            #pragma unroll
            for (int m = 0; m < 4; ++m)
                #pragma unroll
                for (int i = 0; i < 4; ++i)
                    part[wc * 128 + wr * 64 + m * 16 + (lane >> 4) * 4 + i] = ps[m][i];
        __syncthreads();
        if (tid < 128) {
            int gr = r0t + tid;
            if (gr < M) dotout[gr] = part[tid] + part[128 + tid];
        }
    }
}

// ---------------------------------------------------------------------------
// one-time converts (all 11 weight chunks in one launch)
// ---------------------------------------------------------------------------
__launch_bounds__(256)
__global__ void wtrans_all(const float* __restrict__ w0, const float* __restrict__ w1,
                           const float* __restrict__ w2, const float* __restrict__ w3,
                           const float* __restrict__ w4, const float* __restrict__ w5,
                           const float* __restrict__ wcu, const float* __restrict__ wlu,
                           ushort* __restrict__ Wt)
{
    int ch = blockIdx.y;
    const float* W;
    if      (ch == 0) W = w0;
    else if (ch == 1) W = w1;
    else if (ch == 2) W = w2;
    else if (ch == 3) W = w3;
    else if (ch == 4) W = w4;
    else if (ch == 5) W = w5;
    else if (ch == 6) W = wcu;
    else if (ch == 7) W = wcu + 16384;
    else if (ch == 8) W = wlu;
    else if (ch == 9) W = wlu + 16384;
    else              W = wlu + 32768;
    int idx = blockIdx.x * 256 + threadIdx.x;      // 0..16383
    int k = idx >> 7, c = idx & 127;
    Wt[(size_t)ch * CH + c * 128 + k] = f2b(W[k * 128 + c]);
}

// wave per row: fp32 copy to d_out slot0 + bf16 convert + attention dot
__launch_bounds__(256)
__global__ void cvt_dot(const float* __restrict__ in, ushort* __restrict__ out_bf,
                        float* __restrict__ out_f32,
                        const float* __restrict__ att, float* __restrict__ dotout, int M)
{
    int w = (int)((blockIdx.x * (size_t)blockDim.x + threadIdx.x) >> 6);
    if (w >= M) return;
    int lane = threadIdx.x & 63;
    float2 v = *(const float2*)(in + (size_t)w * DIM + lane * 2);
    *(float2*)(out_f32 + (size_t)w * DIM + lane * 2) = v;
    ushort ba = f2b(v.x), bb = f2b(v.y);
    *(unsigned*)(out_bf + (size_t)w * DIM + lane * 2) = (unsigned)ba | ((unsigned)bb << 16);
    float2 a = *(const float2*)(att + lane * 2);
    float s = b2f(ba) * a.x + b2f(bb) * a.y;
    #pragma unroll
    for (int k = 32; k >= 1; k >>= 1) s += __shfl_xor(s, k);
    if (lane == 0) dotout[w] = s;
}

// ---------------------------------------------------------------------------
// CSR build: combined histogram over [cnt_c | cnt_l] -> one scan -> scatter
// ---------------------------------------------------------------------------
__launch_bounds__(256)
__global__ void hist_kernel(const int* __restrict__ le, const int* __restrict__ ce,
                            unsigned* __restrict__ cnt_comb)
{
    int e = blockIdx.x * blockDim.x + threadIdx.x;
    if (e >= ESZ) return;
    atomicAdd(cnt_comb + ce[e], 1u);
    atomicAdd(cnt_comb + CSZ + le[e], 1u);
}

__launch_bounds__(256)
__global__ void scan_partial(const unsigned* __restrict__ in, unsigned* __restrict__ out,
                             unsigned* __restrict__ bsum, int n)
{
    __shared__ unsigned s[256];
    int tid  = threadIdx.x;
    int base = blockIdx.x * 1024 + tid * 4;
    unsigned v[4];
    #pragma unroll
    for (int k = 0; k < 4; ++k) v[k] = (base + k < n) ? in[base + k] : 0u;
    unsigned tsum = v[0] + v[1] + v[2] + v[3];
    s[tid] = tsum;
    __syncthreads();
    for (int off = 1; off < 256; off <<= 1) {
        unsigned t = (tid >= off) ? s[tid - off] : 0u;
        __syncthreads();
        s[tid] += t;
        __syncthreads();
    }
    unsigned run = s[tid] - tsum;
    #pragma unroll
    for (int k = 0; k < 4; ++k) {
        if (base + k < n) out[base + k] = run;
        run += v[k];
    }
    if (tid == 255) bsum[blockIdx.x] = s[255];
}

// 512-capacity top-level scan (2 elems/thread Hillis-Steele)
__launch_bounds__(256)
__global__ void scan_top(unsigned* __restrict__ bsum, int nb)
{
    __shared__ unsigned s[512];
    int tid = threadIdx.x;
    unsigned v0 = (tid < nb) ? bsum[tid] : 0u;
    unsigned v1 = (tid + 256 < nb) ? bsum[tid + 256] : 0u;
    s[tid] = v0; s[tid + 256] = v1;
    __syncthreads();
    for (int off = 1; off < 512; off <<= 1) {
        unsigned t0 = (tid >= off) ? s[tid - off] : 0u;
        unsigned t1 = (tid + 256 >= off) ? s[tid + 256 - off] : 0u;
        __syncthreads();
        s[tid] += t0; s[tid + 256] += t1;
        __syncthreads();
    }
    if (tid < nb) bsum[tid] = s[tid] - v0;
    if (tid + 256 < nb) bsum[tid + 256] = s[tid + 256] - v1;
}

// finalize: bases for c (offset 0) and l (offset -ESZ), cursors, sentinels
__launch_bounds__(256)
__global__ void scan_fixup(const unsigned* __restrict__ scr, const unsigned* __restrict__ bsum,
                           unsigned* __restrict__ base_c, unsigned* __restrict__ base_l,
                           unsigned* __restrict__ cur_c, unsigned* __restrict__ cur_l)
{
    int i = blockIdx.x * blockDim.x + threadIdx.x;
    int n = CSZ + LSZ;
    if (i < n) {
        unsigned v = scr[i] + bsum[i >> 10];
        if (i < CSZ) { base_c[i] = v; cur_c[i] = v; }
        else { unsigned b = v - ESZ; base_l[i - CSZ] = b; cur_l[i - CSZ] = b; }
    }
    if (i == 0) { base_c[CSZ] = ESZ; base_l[LSZ] = ESZ; }
}

__launch_bounds__(256)
__global__ void scatter_kernel(const int* __restrict__ le, const int* __restrict__ ce,
                               unsigned* __restrict__ cur_c, unsigned* __restrict__ cur_l,
                               unsigned* __restrict__ perm_c, unsigned* __restrict__ perm_l,
                               unsigned* __restrict__ le_csr, unsigned* __restrict__ ce_csr)
{
    int e = blockIdx.x * blockDim.x + threadIdx.x;
    if (e >= ESZ) return;
    int lv = le[e], cv = ce[e];
    unsigned p1 = atomicAdd(cur_c + cv, 1u);
    perm_c[p1] = (unsigned)e;
    le_csr[p1] = (unsigned)lv;
    unsigned p2 = atomicAdd(cur_l + lv, 1u);
    perm_l[p2] = (unsigned)e;
    ce_csr[p2] = (unsigned)cv;
}

// ---------------------------------------------------------------------------
// wave-per-clause: fused scores + leaky-relu + softmax (both, ce-segmented)
// + l2c aggregation. Writes W2e (exp vals) + D2 for aggr_l.
// ---------------------------------------------------------------------------
__launch_bounds__(256)
__global__ void aggrC_softmax(const unsigned* __restrict__ base_c, const unsigned* __restrict__ le_csr,
                              const unsigned* __restrict__ perm_c,
                              const float* __restrict__ pc1, const float* __restrict__ ql1,
                              const float* __restrict__ pl2, const float* __restrict__ qc2,
                              float* __restrict__ W2e, float* __restrict__ D2,
                              const ushort* __restrict__ A_bf, ushort* __restrict__ AGC)
{
    int w = (int)((blockIdx.x * (size_t)blockDim.x + threadIdx.x) >> 6);
    if (w >= CSZ) return;
    int lane = threadIdx.x & 63;
    unsigned b0 = base_c[w], b1 = base_c[w + 1];
    float pc = pc1[w], qc = qc2[w];

    // pass 1: segment max (chunks of 64 edges; deg<=64 is one chunk)
    float m1 = -1e30f, m2 = -1e30f;
    for (unsigned j0 = b0; j0 < b1; j0 += 64) {
        unsigned jl = j0 + lane;
        bool act = jl < b1;
        unsigned lv = act ? le_csr[jl] : 0u;
        float s1 = act ? (pc + ql1[lv]) : -1e30f;
        float s2 = act ? (pl2[lv] + qc) : -1e30f;
        s1 = (s1 > 0.f) ? s1 : 0.2f * s1;
        s2 = (s2 > 0.f) ? s2 : 0.2f * s2;
        m1 = fmaxf(m1, s1); m2 = fmaxf(m2, s2);
    }
    #pragma unroll
    for (int k = 32; k >= 1; k >>= 1) {
        m1 = fmaxf(m1, __shfl_xor(m1, k));
        m2 = fmaxf(m2, __shfl_xor(m2, k));
    }

    // pass 2: denominators + W2e scatter
    float d1 = 0.f, d2 = 0.f;
    for (unsigned j0 = b0; j0 < b1; j0 += 64) {
        unsigned jl = j0 + lane;
        bool act = jl < b1;
        unsigned lv = act ? le_csr[jl] : 0u;
        float s1 = pc + ql1[lv];  s1 = (s1 > 0.f) ? s1 : 0.2f * s1;
        float s2 = pl2[lv] + qc;  s2 = (s2 > 0.f) ? s2 : 0.2f * s2;
        float e1 = act ? __expf(s1 - m1) : 0.f;
        float e2 = act ? __expf(s2 - m2) : 0.f;
        d1 += e1; d2 += e2;
        if (act) W2e[perm_c[jl]] = e2;
    }
    #pragma unroll
    for (int k = 32; k >= 1; k >>= 1) {
        d1 += __shfl_xor(d1, k);
        d2 += __shfl_xor(d2, k);
    }
    if (lane == 0) D2[w] = d2;

    // pass 3: weighted aggregation of A rows
    float invd = 1.f / (d1 + 1e-16f);
    int d = lane * 2;
    float ax = 0.f, ay = 0.f;
    for (unsigned j0 = b0; j0 < b1; j0 += 64) {
        unsigned jl = j0 + lane;
        bool act = jl < b1;
        unsigned lv = act ? le_csr[jl] : 0u;
        float s1 = pc + ql1[lv];  s1 = (s1 > 0.f) ? s1 : 0.2f * s1;
        float e1 = act ? __expf(s1 - m1) : 0.f;
        int cnt = (int)min(64u, b1 - j0);
        for (int j = 0; j < cnt; ++j) {
            float wt = __shfl(e1, j) * invd;
            unsigned row = __shfl(lv, j);
            unsigned av = *(const unsigned*)(A_bf + (size_t)row * DIM + d);
            ax = fmaf(wt, b2f(av & 0xffffu), ax);
            ay = fmaf(wt, b2f(av >> 16), ay);
        }
    }
    *(unsigned*)(AGC + (size_t)w * DIM + d) = (unsigned)f2b(ax) | ((unsigned)f2b(ay) << 16);
}

// wave per literal: AGL[l] = sum_j (W2e[perm_l[j]]/D2[ce_csr[j]]) * B[ce_csr[j]]
__launch_bounds__(256)
__global__ void aggr_l(const unsigned* __restrict__ base_l, const unsigned* __restrict__ ce_csr,
                       const unsigned* __restrict__ perm_l,
                       const float* __restrict__ W2e, const float* __restrict__ D2,
                       const ushort* __restrict__ B_bf, ushort* __restrict__ AGL)
{
    int w = (int)((blockIdx.x * (size_t)blockDim.x + threadIdx.x) >> 6);
    if (w >= LSZ) return;
    int lane = threadIdx.x & 63;
    int d = lane * 2;
    unsigned b0 = base_l[w], b1 = base_l[w + 1];
    float ax = 0.f, ay = 0.f;
    for (unsigned j = b0; j < b1; ++j) {
        unsigned e = perm_l[j];
        unsigned cv = ce_csr[j];
        float wt = W2e[e] / (D2[cv] + 1e-16f);
        unsigned bv = *(const unsigned*)(B_bf + (size_t)cv * DIM + d);
        ax = fmaf(wt, b2f(bv & 0xffffu), ax);
        ay = fmaf(wt, b2f(bv >> 16), ay);
    }
    *(unsigned*)(AGL + (size_t)w * DIM + d) = (unsigned)f2b(ax) | ((unsigned)f2b(ay) << 16);
}

extern "C" void kernel_launch(void* const* d_in, const int* in_sizes, int n_in,
                              void* d_out, int out_size, void* d_ws, size_t ws_size,
                              hipStream_t stream)
{
    const int*   le      = (const int*)  d_in[2];
    const int*   ce      = (const int*)  d_in[3];
    const float* l_emb0  = (const float*)d_in[4];
    const float* c_emb0  = (const float*)d_in[5];
    const float* l2c_w1  = (const float*)d_in[6];
    const float* l2c_b1  = (const float*)d_in[7];
    const float* l2c_w2  = (const float*)d_in[8];
    const float* l2c_b2  = (const float*)d_in[9];
    const float* c2l_w1  = (const float*)d_in[10];
    const float* c2l_b1  = (const float*)d_in[11];
    const float* c2l_w2  = (const float*)d_in[12];
    const float* c2l_b2  = (const float*)d_in[13];
    const float* l2l_w1  = (const float*)d_in[14];
    const float* l2l_b1  = (const float*)d_in[15];
    const float* l2l_w2  = (const float*)d_in[16];
    const float* l2l_b2  = (const float*)d_in[17];
    const float* c_att   = (const float*)d_in[18];
    const float* c_upd_w = (const float*)d_in[19];
    const float* c_upd_b = (const float*)d_in[20];
    const float* l_att   = (const float*)d_in[21];
    const float* l_upd_w = (const float*)d_in[22];
    const float* l_upd_b = (const float*)d_in[23];

    float* out = (float*)d_out;
    float* outL[3] = { out,
                       out + (size_t)LSZ * DIM,
                       out + 2 * (size_t)LSZ * DIM };
    float* outC[3] = { out + 3 * (size_t)LSZ * DIM,
                       out + 3 * (size_t)LSZ * DIM + (size_t)CSZ * DIM,
                       out + 3 * (size_t)LSZ * DIM + 2 * (size_t)CSZ * DIM };

    char* p = (char*)d_ws;
    ushort* A_bf   = (ushort*)p; p += (size_t)LSZ * DIM * 2;
    ushort* B_bf   = (ushort*)p; p += (size_t)CSZ * DIM * 2;
    ushort* AGC_bf = (ushort*)p; p += (size_t)CSZ * DIM * 2;
    ushort* AGL_bf = (ushort*)p; p += (size_t)LSZ * DIM * 2;
    ushort* l_bf0  = (ushort*)p; p += (size_t)LSZ * DIM * 2;
    ushort* l_bf1  = (ushort*)p; p += (size_t)LSZ * DIM * 2;
    ushort* c_bf0  = (ushort*)p; p += (size_t)CSZ * DIM * 2;
    ushort* c_bf1  = (ushort*)p; p += (size_t)CSZ * DIM * 2;
    ushort* Wt     = (ushort*)p; p += (size_t)11 * CH * 2;
    float* W2e   = (float*)p; p += (size_t)ESZ * 4;
    float* pc1 = (float*)p; p += (size_t)CSZ * 4;
    float* qc2 = (float*)p; p += (size_t)CSZ * 4;
    float* ql1 = (float*)p; p += (size_t)LSZ * 4;
    float* pl2 = (float*)p; p += (size_t)LSZ * 4;
    float* D2  = (float*)p; p += (size_t)CSZ * 4;
    unsigned* base_c   = (unsigned*)p; p += (size_t)(CSZ + 1) * 4;
    unsigned* base_l   = (unsigned*)p; p += (size_t)(LSZ + 1) * 4;
    unsigned* cur_c    = (unsigned*)p; p += (size_t)CSZ * 4;
    unsigned* cur_l    = (unsigned*)p; p += (size_t)LSZ * 4;
    unsigned* cnt_comb = (unsigned*)p; p += (size_t)(CSZ + LSZ) * 4;
    unsigned* scr_comb = (unsigned*)p; p += (size_t)(CSZ + LSZ) * 4;
    unsigned* perm_c = (unsigned*)p; p += (size_t)ESZ * 4;
    unsigned* perm_l = (unsigned*)p; p += (size_t)ESZ * 4;
    unsigned* le_csr = (unsigned*)p; p += (size_t)ESZ * 4;
    unsigned* ce_csr = (unsigned*)p; p += (size_t)ESZ * 4;
    unsigned* bsum   = (unsigned*)p; p += 1024 * 4;

    const int GL128 = (LSZ + 127) / 128;
    const int GC128 = (CSZ + 127) / 128;
    const int GE_THR = (ESZ + 255) / 256;
    const int GC_WAVE = (CSZ + 3) / 4;
    const int GL_WAVE = (LSZ + 3) / 4;
    const int NCOMB = CSZ + LSZ;

    // one-time converts (+ iter-0 attention dots pc1/pl2 fused in)
    cvt_dot<<<GL_WAVE, 256, 0, stream>>>(l_emb0, l_bf0, outL[0], l_att, pl2, LSZ);
    cvt_dot<<<GC_WAVE, 256, 0, stream>>>(c_emb0, c_bf0, outC[0], c_att, pc1, CSZ);
    wtrans_all<<<dim3(64, 11), 256, 0, stream>>>(l2c_w1, l2c_w2, c2l_w1, c2l_w2,
                                                 l2l_w1, l2l_w2, c_upd_w, l_upd_w, Wt);

    // CSR build (combined c|l scan)
    hipMemsetAsync(cnt_comb, 0, (size_t)NCOMB * sizeof(unsigned), stream);
    hist_kernel<<<GE_THR, 256, 0, stream>>>(le, ce, cnt_comb);
    int nb = (NCOMB + 1023) / 1024;
    scan_partial<<<nb, 256, 0, stream>>>(cnt_comb, scr_comb, bsum, NCOMB);
    scan_top<<<1, 256, 0, stream>>>(bsum, nb);
    scan_fixup<<<(NCOMB + 255) / 256, 256, 0, stream>>>(scr_comb, bsum, base_c, base_l, cur_c, cur_l);
    scatter_kernel<<<GE_THR, 256, 0, stream>>>(le, ce, cur_c, cur_l, perm_c, perm_l, le_csr, ce_csr);

    for (int it = 0; it < 2; ++it) {
        const ushort* l_in = (it == 0) ? l_bf0 : l_bf1;
        const ushort* c_in = (it == 0) ? c_bf0 : c_bf1;

        // message MLPs with fused attention dots (ql1, qc2)
        mlp2_fused<false, true><<<GL128, 256, 0, stream>>>(l_in, Wt + 0 * CH, Wt + 1 * CH,
                                                           l2c_b1, l2c_b2, A_bf,
                                                           c_att + DIM, ql1, LSZ);
        mlp2_fused<false, true><<<GC128, 256, 0, stream>>>(c_in, Wt + 2 * CH, Wt + 3 * CH,
                                                           c2l_b1, c2l_b2, B_bf,
                                                           l_att + DIM, qc2, CSZ);

        // fused scores + softmax + l2c aggregation (writes W2e/D2 for aggr_l)
        aggrC_softmax<<<GC_WAVE, 256, 0, stream>>>(base_c, le_csr, perm_c,
                                                   pc1, ql1, pl2, qc2, W2e, D2, A_bf, AGC_bf);
        aggr_l<<<GL_WAVE, 256, 0, stream>>>(base_l, ce_csr, perm_l, W2e, D2, B_bf, AGL_bf);

        // l2l message (pair-swapped input), overwrites A_bf (consumed by aggrC)
        mlp2_fused<true, false><<<GL128, 256, 0, stream>>>(l_in, Wt + 4 * CH, Wt + 5 * CH,
                                                           l2l_b1, l2l_b2, A_bf,
                                                           nullptr, nullptr, LSZ);

        // updates
        if (it == 0) {
            upd_gemm<2, true, true><<<GC128, 256, 0, stream>>>(c_in, AGC_bf, nullptr,
                                                               Wt + 6 * CH, c_upd_b, outC[1], c_bf1,
                                                               c_att, pc1, CSZ);
            upd_gemm<3, true, true><<<GL128, 256, 0, stream>>>(l_in, AGL_bf, A_bf,
                                                               Wt + 8 * CH, l_upd_b, outL[1], l_bf1,
                                                               l_att, pl2, LSZ);
        } else {
            upd_gemm<2, false, false><<<GC128, 256, 0, stream>>>(c_in, AGC_bf, nullptr,
                                                                 Wt + 6 * CH, c_upd_b, outC[2], c_bf1,
                                                                 c_att, pc1, CSZ);
            upd_gemm<3, false, false><<<GL128, 256, 0, stream>>>(l_in, AGL_bf, A_bf,
                                                                 Wt + 8 * CH, l_upd_b, outL[2], l_bf1,
                                                                 l_att, pl2, LSZ);
        }
    }
}